// Round 4
// baseline (715.084 us; speedup 1.0000x reference)
//
#include <hip/hip_runtime.h>

// ---------------------------------------------------------------------------
// 2-layer GCN: out = log_softmax( A_hat( relu( A_hat(X W1)+b1 ) W2 ) + b2 )
// A_hat = D^-1/2 (A+I) D^-1/2, deg = indegree(dst)+1 (self-loop).
// R4: two-level bucketed CSR build. R3 post-mortem: random 4B scatter into
// 25.6MB forced ~200MB of random HBM RMW traffic (WRITE_SIZE 123MB, ~950GB/s
// random-access plateau). Now: pass1a bins edges (packed u32) into 391
// buckets x 4 cursor segments (dense tail appends, ~6.4MB), pass1b builds
// padded rows inside each bucket's private 64KB window (dense, XCD-local).
// Aggregation: wave-per-node, shfl broadcast (no LDS/barriers), bf16x2 lanes.
// ---------------------------------------------------------------------------

#define NN 100000
#define EE 1600000
#define F_IN 512
#define HID 128
#define CLS 64
#define CAP 64            // padded CSR row capacity (== wavesize)
#define NBUCK 391         // ceil(NN/256)
#define SCAP 1536         // per (bucket,segment) record capacity; mean 1023, +16 sigma
#define BUILD_BLOCKS 782  // ceil(EE / 2048)

typedef __bf16 v8bf __attribute__((ext_vector_type(8)));
typedef float v4f __attribute__((ext_vector_type(4)));
typedef unsigned int uint;
typedef unsigned short ushort;

__device__ __forceinline__ float bf_lo(uint u) { return __uint_as_float(u << 16); }
__device__ __forceinline__ float bf_hi(uint u) { return __uint_as_float(u & 0xffff0000u); }

// ------------------------- small prep kernels ------------------------------

__global__ void cvt_weights(const float* __restrict__ W1, const float* __restrict__ W2,
                            __bf16* __restrict__ W1t, __bf16* __restrict__ W2t) {
    int i = blockIdx.x * 256 + threadIdx.x;
    if (i < F_IN * HID) { int k = i / HID, n = i % HID; W1t[(size_t)n * F_IN + k] = (__bf16)W1[i]; }
    if (i < HID * CLS)  { int k = i / CLS,  n = i % CLS; W2t[(size_t)n * HID + k] = (__bf16)W2[i]; }
}

// ------------- fused: edge binning (pass 1a) + GEMM1 (X @ W1) --------------
// build blocks: 8 edges/thread; rec = (s<<8)|(d&255) (s<2^17 -> 25 bits).
// Appends to bucket-segment tails: dense writes, L2-aggregated.
// gemm blocks: 128x128 tile, BK=32 (LDS 20.5KB -> 7 blk/CU, all co-resident).
template<int BM, int BN, int BK, int K>
__global__ __launch_bounds__(256) void fused_bin_gemm1(
        const float* __restrict__ X, const __bf16* __restrict__ Bt,
        __bf16* __restrict__ Out, int M,
        const int* __restrict__ src, const int* __restrict__ dst,
        int* __restrict__ bcnt4, uint* __restrict__ bbuf) {
    constexpr int SA = BK + 8;
    constexpr int SB = BK + 8;
    __shared__ __align__(16) __bf16 As[BM * SA];
    __shared__ __align__(16) __bf16 Bs[BN * SB];
    const int tid = threadIdx.x;

    if (blockIdx.x < BUILD_BLOCKS) {
        const int seg = blockIdx.x & 3;
        int base = blockIdx.x * 2048 + tid;
        int s[8], d[8], p[8], slot[8];
        bool ok[8];
        #pragma unroll
        for (int j = 0; j < 8; ++j) {
            int idx = base + j * 256;
            ok[j] = idx < EE;
            int ii = ok[j] ? idx : 0;
            d[j] = dst[ii];
            s[j] = src[ii];
            unsigned ud = (unsigned)d[j]; if (ud >= NN) ud = 0; d[j] = (int)ud;
            unsigned us = (unsigned)s[j]; if (us >= NN) us = 0; s[j] = (int)us;
            slot[j] = (d[j] >> 8) * 4 + seg;
        }
        #pragma unroll
        for (int j = 0; j < 8; ++j)
            p[j] = ok[j] ? atomicAdd(&bcnt4[slot[j]], 1) : SCAP;
        #pragma unroll
        for (int j = 0; j < 8; ++j)
            if (ok[j] && p[j] < SCAP)
                bbuf[(size_t)slot[j] * SCAP + p[j]] = ((uint)s[j] << 8) | ((uint)d[j] & 255u);
        return;
    }

    const int m0 = (blockIdx.x - BUILD_BLOCKS) * BM;
    constexpr int WM = BM / 2, WN = BN / 2;
    constexpr int MT = WM / 16, NT = WN / 16;
    const int w = tid >> 6, lane = tid & 63;
    const int wm = w & 1, wn = w >> 1;
    const int lr = lane & 15;
    const int lq = lane >> 4;

    v4f acc[MT][NT] = {};

    for (int k0 = 0; k0 < K; k0 += BK) {
        {   // stage A (f32 -> bf16)
            constexpr int CH = BM * (BK / 8);
            for (int sgi = tid; sgi < CH; sgi += 256) {
                int row = sgi / (BK / 8), c8 = sgi % (BK / 8);
                int gr = m0 + row; if (gr >= M) gr = M - 1;
                const float* g = X + (size_t)gr * K + k0 + c8 * 8;
                float4 v0 = *(const float4*)g;
                float4 v1 = *(const float4*)(g + 4);
                __bf16 b[8];
                b[0] = (__bf16)v0.x; b[1] = (__bf16)v0.y; b[2] = (__bf16)v0.z; b[3] = (__bf16)v0.w;
                b[4] = (__bf16)v1.x; b[5] = (__bf16)v1.y; b[6] = (__bf16)v1.z; b[7] = (__bf16)v1.w;
                *(uint4*)&As[row * SA + c8 * 8] = *(uint4*)b;
            }
        }
        {   // stage B rows (Bt already [n][k])
            constexpr int CH = BN * (BK / 8);
            for (int sgi = tid; sgi < CH; sgi += 256) {
                int n = sgi / (BK / 8), c8 = sgi % (BK / 8);
                uint4 val = *(const uint4*)(Bt + (size_t)n * K + k0 + c8 * 8);
                *(uint4*)&Bs[n * SB + c8 * 8] = val;
            }
        }
        __syncthreads();
        #pragma unroll
        for (int kk = 0; kk < BK; kk += 32) {
            v8bf a[MT], bfr[NT];
            #pragma unroll
            for (int i = 0; i < MT; ++i)
                a[i] = *(const v8bf*)&As[(wm * WM + i * 16 + lr) * SA + kk + lq * 8];
            #pragma unroll
            for (int j = 0; j < NT; ++j)
                bfr[j] = *(const v8bf*)&Bs[(wn * WN + j * 16 + lr) * SB + kk + lq * 8];
            #pragma unroll
            for (int i = 0; i < MT; ++i)
                #pragma unroll
                for (int j = 0; j < NT; ++j)
                    acc[i][j] = __builtin_amdgcn_mfma_f32_16x16x32_bf16(a[i], bfr[j], acc[i][j], 0, 0, 0);
        }
        __syncthreads();
    }
    #pragma unroll
    for (int i = 0; i < MT; ++i)
        #pragma unroll
        for (int j = 0; j < NT; ++j)
            #pragma unroll
            for (int r = 0; r < 4; ++r) {
                int row = m0 + wm * WM + i * 16 + lq * 4 + r;
                if (row < M) {
                    int col = wn * WN + j * 16 + lr;
                    Out[(size_t)row * BN + col] = (__bf16)acc[i][j][r];
                }
            }
}

// ---------------- pass 1b: per-bucket padded-row construction --------------
// One block per bucket. All csr_pad writes land in this bucket's private
// 64KB window (dense, single-XCD). Emits cnt + inv_sqrt too.
__global__ __launch_bounds__(256) void build_rows(const uint* __restrict__ bbuf,
                                                  const int* __restrict__ bcnt4,
                                                  int* __restrict__ cnt,
                                                  float* __restrict__ inv,
                                                  int* __restrict__ csr_pad) {
    __shared__ int lcnt[256];
    const int b = blockIdx.x, tid = threadIdx.x;
    lcnt[tid] = 0;
    __syncthreads();
    const int v0 = b * 256;
    #pragma unroll
    for (int seg = 0; seg < 4; ++seg) {
        int slot = b * 4 + seg;
        int n = min(bcnt4[slot], SCAP);
        const uint* rp = bbuf + (size_t)slot * SCAP;
        for (int i = tid; i < n; i += 256) {
            uint rec = rp[i];
            int vl = (int)(rec & 255u);
            int s  = (int)(rec >> 8);
            int p = atomicAdd(&lcnt[vl], 1);
            if (p < CAP) csr_pad[(size_t)(v0 + vl) * CAP + p] = s;
        }
    }
    __syncthreads();
    int v = v0 + tid;
    if (v < NN) {
        cnt[v] = lcnt[tid];
        inv[v] = rsqrtf((float)(lcnt[tid] + 1));
    }
}

// ------------------------------ GEMM2 (bf16 in) ----------------------------
template<int BM, int BN, int BK, int K>
__global__ __launch_bounds__(256) void gemm_bt(const __bf16* __restrict__ A,
                                               const __bf16* __restrict__ Bt,
                                               __bf16* __restrict__ Out, int M) {
    constexpr int SA = BK + 8;
    constexpr int SB = BK + 8;
    __shared__ __align__(16) __bf16 As[BM * SA];
    __shared__ __align__(16) __bf16 Bs[BN * SB];
    const int tid = threadIdx.x;
    const int m0 = blockIdx.x * BM;
    constexpr int WM = BM / 2, WN = BN / 2;
    constexpr int MT = WM / 16, NT = WN / 16;
    const int w = tid >> 6, lane = tid & 63;
    const int wm = w & 1, wn = w >> 1;
    const int lr = lane & 15;
    const int lq = lane >> 4;

    v4f acc[MT][NT] = {};

    for (int k0 = 0; k0 < K; k0 += BK) {
        {
            constexpr int CH = BM * (BK / 8);
            for (int s = tid; s < CH; s += 256) {
                int row = s / (BK / 8), c8 = s % (BK / 8);
                int gr = m0 + row; if (gr >= M) gr = M - 1;
                uint4 val = *(const uint4*)(A + (size_t)gr * K + k0 + c8 * 8);
                *(uint4*)&As[row * SA + c8 * 8] = val;
            }
        }
        {
            constexpr int CH = BN * (BK / 8);
            for (int s = tid; s < CH; s += 256) {
                int n = s / (BK / 8), c8 = s % (BK / 8);
                uint4 val = *(const uint4*)(Bt + (size_t)n * K + k0 + c8 * 8);
                *(uint4*)&Bs[n * SB + c8 * 8] = val;
            }
        }
        __syncthreads();
        #pragma unroll
        for (int kk = 0; kk < BK; kk += 32) {
            v8bf a[MT], bfr[NT];
            #pragma unroll
            for (int i = 0; i < MT; ++i)
                a[i] = *(const v8bf*)&As[(wm * WM + i * 16 + lr) * SA + kk + lq * 8];
            #pragma unroll
            for (int j = 0; j < NT; ++j)
                bfr[j] = *(const v8bf*)&Bs[(wn * WN + j * 16 + lr) * SB + kk + lq * 8];
            #pragma unroll
            for (int i = 0; i < MT; ++i)
                #pragma unroll
                for (int j = 0; j < NT; ++j)
                    acc[i][j] = __builtin_amdgcn_mfma_f32_16x16x32_bf16(a[i], bfr[j], acc[i][j], 0, 0, 0);
        }
        __syncthreads();
    }
    #pragma unroll
    for (int i = 0; i < MT; ++i)
        #pragma unroll
        for (int j = 0; j < NT; ++j)
            #pragma unroll
            for (int r = 0; r < 4; ++r) {
                int row = m0 + wm * WM + i * 16 + lq * 4 + r;
                if (row < M) {
                    int col = wn * WN + j * 16 + lr;
                    Out[(size_t)row * BN + col] = (__bf16)acc[i][j][r];
                }
            }
}

// --------------------------- aggregation kernels ---------------------------
// Wave-per-node: lane l reads csr row element l (CAP==64), coefs computed
// per-lane, broadcast via __shfl. No LDS, no barriers.

// HID=128: lane handles features {2l, 2l+1} as packed bf16x2 (uint).
__global__ __launch_bounds__(256) void agg_relu_w(const uint* __restrict__ Hin,
                                                  const float* __restrict__ inv,
                                                  const int* __restrict__ cnt,
                                                  const int* __restrict__ csr_pad,
                                                  const float* __restrict__ bias,
                                                  uint* __restrict__ Hout) {
    const int wid = threadIdx.x >> 6, lane = threadIdx.x & 63;
    const int v = blockIdx.x * 4 + wid;
    if (v >= NN) return;
    const float isv = inv[v];
    const int n_e = min(cnt[v], CAP);
    int sidx = csr_pad[(size_t)v * CAP + lane];
    if (lane >= n_e) sidx = 0;            // poison guard
    float c = inv[sidx] * isv;
    uint u = Hin[(size_t)v * 64 + lane];
    float ax = bf_lo(u) * isv * isv;
    float ay = bf_hi(u) * isv * isv;
    int j = 0;
    for (; j + 3 < n_e; j += 4) {
        int s0 = __shfl(sidx, j), s1 = __shfl(sidx, j + 1);
        int s2 = __shfl(sidx, j + 2), s3 = __shfl(sidx, j + 3);
        float c0 = __shfl(c, j), c1 = __shfl(c, j + 1);
        float c2 = __shfl(c, j + 2), c3 = __shfl(c, j + 3);
        uint h0 = Hin[(size_t)s0 * 64 + lane];
        uint h1 = Hin[(size_t)s1 * 64 + lane];
        uint h2 = Hin[(size_t)s2 * 64 + lane];
        uint h3 = Hin[(size_t)s3 * 64 + lane];
        ax += c0 * bf_lo(h0); ay += c0 * bf_hi(h0);
        ax += c1 * bf_lo(h1); ay += c1 * bf_hi(h1);
        ax += c2 * bf_lo(h2); ay += c2 * bf_hi(h2);
        ax += c3 * bf_lo(h3); ay += c3 * bf_hi(h3);
    }
    for (; j < n_e; ++j) {
        int s0 = __shfl(sidx, j);
        float c0 = __shfl(c, j);
        uint h0 = Hin[(size_t)s0 * 64 + lane];
        ax += c0 * bf_lo(h0); ay += c0 * bf_hi(h0);
    }
    float ox = fmaxf(ax + bias[2 * lane], 0.f);
    float oy = fmaxf(ay + bias[2 * lane + 1], 0.f);
    __bf16 blo = (__bf16)ox, bhi = (__bf16)oy;
    uint res = (uint)*(ushort*)&blo | ((uint)*(ushort*)&bhi << 16);
    Hout[(size_t)v * 64 + lane] = res;
}

// CLS=64: lane == class. Gather rows of 64 bf16 (128B), softmax via shfl.
__global__ __launch_bounds__(256) void agg_softmax_w(const ushort* __restrict__ Hin,
                                                     const float* __restrict__ inv,
                                                     const int* __restrict__ cnt,
                                                     const int* __restrict__ csr_pad,
                                                     const float* __restrict__ bias,
                                                     float* __restrict__ out) {
    const int wid = threadIdx.x >> 6, lane = threadIdx.x & 63;
    const int v = blockIdx.x * 4 + wid;
    if (v >= NN) return;
    const float isv = inv[v];
    const int n_e = min(cnt[v], CAP);
    int sidx = csr_pad[(size_t)v * CAP + lane];
    if (lane >= n_e) sidx = 0;
    float c = inv[sidx] * isv;
    uint u = (uint)Hin[(size_t)v * 64 + lane];
    float acc = __uint_as_float(u << 16) * isv * isv;
    int j = 0;
    for (; j + 3 < n_e; j += 4) {
        int s0 = __shfl(sidx, j), s1 = __shfl(sidx, j + 1);
        int s2 = __shfl(sidx, j + 2), s3 = __shfl(sidx, j + 3);
        float c0 = __shfl(c, j), c1 = __shfl(c, j + 1);
        float c2 = __shfl(c, j + 2), c3 = __shfl(c, j + 3);
        uint h0 = (uint)Hin[(size_t)s0 * 64 + lane];
        uint h1 = (uint)Hin[(size_t)s1 * 64 + lane];
        uint h2 = (uint)Hin[(size_t)s2 * 64 + lane];
        uint h3 = (uint)Hin[(size_t)s3 * 64 + lane];
        acc += c0 * __uint_as_float(h0 << 16);
        acc += c1 * __uint_as_float(h1 << 16);
        acc += c2 * __uint_as_float(h2 << 16);
        acc += c3 * __uint_as_float(h3 << 16);
    }
    for (; j < n_e; ++j) {
        int s0 = __shfl(sidx, j);
        float c0 = __shfl(c, j);
        uint h0 = (uint)Hin[(size_t)s0 * 64 + lane];
        acc += c0 * __uint_as_float(h0 << 16);
    }
    float o = acc + bias[lane];
    float m = o;
    #pragma unroll
    for (int off = 32; off >= 1; off >>= 1) m = fmaxf(m, __shfl_xor(m, off, 64));
    float e = __expf(o - m);
    float s = e;
    #pragma unroll
    for (int off = 32; off >= 1; off >>= 1) s += __shfl_xor(s, off, 64);
    out[(size_t)v * CLS + lane] = (o - m) - __logf(s);
}

// ------------------------------- launcher ----------------------------------

extern "C" void kernel_launch(void* const* d_in, const int* in_sizes, int n_in,
                              void* d_out, int out_size, void* d_ws, size_t ws_size,
                              hipStream_t stream) {
    const float* x   = (const float*)d_in[0];
    const int*   src = (const int*)d_in[1];
    const int*   dst = (const int*)d_in[2];
    const float* W1  = (const float*)d_in[3];
    const float* b1  = (const float*)d_in[4];
    const float* W2  = (const float*)d_in[5];
    const float* b2  = (const float*)d_in[6];
    float* out = (float*)d_out;

    char* p = (char*)d_ws;
    size_t off = 0;
    auto alloc = [&](size_t bytes) {
        off = (off + 255) & ~(size_t)255;
        char* r = p + off;
        off += bytes;
        return r;
    };
    int*    cnt     = (int*)alloc(NN * 4);
    float*  inv     = (float*)alloc(NN * 4);
    int*    bcnt4   = (int*)alloc((size_t)NBUCK * 4 * 4);
    uint*   bbuf    = (uint*)alloc((size_t)NBUCK * 4 * SCAP * 4);   // 9.6 MB
    int*    csr_pad = (int*)alloc((size_t)NN * CAP * 4);            // 25.6 MB
    __bf16* W1t     = (__bf16*)alloc((size_t)F_IN * HID * 2);
    __bf16* W2t     = (__bf16*)alloc((size_t)HID * CLS * 2);
    __bf16* P1b     = (__bf16*)alloc((size_t)NN * HID * 2);
    __bf16* H1b     = (__bf16*)alloc((size_t)NN * HID * 2);
    __bf16* P2b     = (__bf16*)alloc((size_t)NN * CLS * 2);

    hipMemsetAsync(bcnt4, 0, (size_t)NBUCK * 4 * 4, stream);
    cvt_weights<<<(F_IN * HID + 255) / 256, 256, 0, stream>>>(W1, W2, W1t, W2t);

    // pass1a binning (782 blocks) + GEMM1 X@W1 (782 blocks), fused
    const int MB1 = (NN + 127) / 128;    // 782
    fused_bin_gemm1<128, HID, 32, F_IN><<<BUILD_BLOCKS + MB1, 256, 0, stream>>>(
        x, W1t, P1b, NN, src, dst, bcnt4, bbuf);

    build_rows<<<NBUCK, 256, 0, stream>>>(bbuf, bcnt4, cnt, inv, csr_pad);

    agg_relu_w<<<(NN + 3) / 4, 256, 0, stream>>>((const uint*)P1b, inv, cnt, csr_pad, b1, (uint*)H1b);

    gemm_bt<128, CLS, 128, HID><<<MB1, 256, 0, stream>>>(H1b, W2t, P2b, NN);

    agg_softmax_w<<<(NN + 3) / 4, 256, 0, stream>>>((const ushort*)P2b, inv, cnt, csr_pad, b2, out);
}

// Round 5
// 561.754 us; speedup vs baseline: 1.2729x; 1.2729x over previous
//
#include <hip/hip_runtime.h>

// ---------------------------------------------------------------------------
// 2-layer GCN: out = log_softmax( A_hat( relu( A_hat(X W1)+b1 ) W2 ) + b2 )
// A_hat = D^-1/2 (A+I) D^-1/2, deg = indegree(dst)+1 (self-loop).
// R5: ZERO global atomics. R4 post-mortem: 1.6M device-scope atomics on 1564
// counters + cross-XCD tail-line ping-pong = 344us wall. Now: per-block LDS
// histogram (392 buckets) -> LDS scan -> LDS scatter -> one dense 16KB
// copy-out per block + (bucket,block) offset/count tables. build_rows then
// owns one bucket per block (exclusive 64KB csr_pad window, LDS slot
// counters). Agg: wave-per-node shfl broadcast (R4, kept).
// ---------------------------------------------------------------------------

#define NN 100000
#define EE 1600000
#define F_IN 512
#define HID 128
#define CLS 64
#define CAP 64            // padded CSR row capacity (== wavesize)
#define NBUCK 391         // ceil(NN/256) buckets of 256 nodes
#define EPB 4096          // edges per build block
#define EPT 16            // edges per thread (EPB/256)
#define NBLK 391          // ceil(EE/EPB) build blocks

typedef __bf16 v8bf __attribute__((ext_vector_type(8)));
typedef float v4f __attribute__((ext_vector_type(4)));
typedef unsigned int uint;
typedef unsigned short ushort;

__device__ __forceinline__ float bf_lo(uint u) { return __uint_as_float(u << 16); }
__device__ __forceinline__ float bf_hi(uint u) { return __uint_as_float(u & 0xffff0000u); }

// ------------------------- small prep kernels ------------------------------

__global__ void cvt_weights(const float* __restrict__ W1, const float* __restrict__ W2,
                            __bf16* __restrict__ W1t, __bf16* __restrict__ W2t) {
    int i = blockIdx.x * 256 + threadIdx.x;
    if (i < F_IN * HID) { int k = i / HID, n = i % HID; W1t[(size_t)n * F_IN + k] = (__bf16)W1[i]; }
    if (i < HID * CLS)  { int k = i / CLS,  n = i % CLS; W2t[(size_t)n * HID + k] = (__bf16)W2[i]; }
}

// ------------- fused: LDS edge binning (pass 1a) + GEMM1 (X @ W1) ----------
// build blocks [0,NBLK): 4096 edges -> LDS hist/scan/scatter -> dense copy.
// gemm blocks [NBLK,...): 128x128 tile, BK=32. LDS is a union (20480 B both).
// 16x16x32 bf16 MFMA: A lane m=lane&15,k=(lane>>4)*8+j; B same;
// C/D: col=lane&15, row=(lane>>4)*4+reg.
template<int BM, int BN, int BK, int K>
__global__ __launch_bounds__(256) void fused_bin_gemm1(
        const float* __restrict__ X, const __bf16* __restrict__ Bt,
        __bf16* __restrict__ Out, int M,
        const int* __restrict__ src, const int* __restrict__ dst,
        int* __restrict__ boff, int* __restrict__ bcnt, uint* __restrict__ bbuf) {
    constexpr int SA = BK + 8;
    constexpr int SB = BK + 8;
    constexpr int LDS_BYTES = (BM * SA + BN * SB) * 2;   // 20480 for 128/128/32
    static_assert(EPB * 4 + (NBUCK + 1) * 8 + 49 * 4 <= LDS_BYTES, "build LDS fits");
    __shared__ __align__(16) char smem[LDS_BYTES];
    const int tid = threadIdx.x;

    if (blockIdx.x < NBLK) {
        // ---------------- binning path (LDS only) ----------------
        uint* lrec  = (uint*)smem;                        // EPB records
        int*  lhist = (int*)(smem + EPB * 4);             // NBUCK+1 (last = invalid)
        int*  loff  = lhist + (NBUCK + 1);
        int*  asum  = loff + (NBUCK + 1);                 // 49 group sums
        const int blk = blockIdx.x;
        const int base = blk * EPB;
        for (int i = tid; i < NBUCK + 1; i += 256) lhist[i] = 0;
        __syncthreads();
        uint rec[EPT]; int bk[EPT], pos[EPT];
        #pragma unroll
        for (int j = 0; j < EPT; ++j) {
            int idx = base + tid + j * 256;               // coalesced
            bool ok = idx < EE;
            int ii = ok ? idx : 0;
            unsigned ud = (unsigned)dst[ii]; if (ud >= NN) ud = 0;
            unsigned us = (unsigned)src[ii]; if (us >= NN) us = 0;
            rec[j] = (us << 8) | (ud & 255u);
            bk[j] = ok ? (int)(ud >> 8) : NBUCK;
            pos[j] = atomicAdd(&lhist[bk[j]], 1);         // LDS atomic
        }
        __syncthreads();
        // exclusive scan of lhist[0..391] (49 groups of 8)
        if (tid < 49) {
            int s = 0;
            #pragma unroll
            for (int k = 0; k < 8; ++k) s += lhist[tid * 8 + k];
            asum[tid] = s;
        }
        __syncthreads();
        if (tid == 0) {
            int run = 0;
            for (int g = 0; g < 49; ++g) { int t = asum[g]; asum[g] = run; run += t; }
        }
        __syncthreads();
        if (tid < 49) {
            int run = asum[tid];
            #pragma unroll
            for (int k = 0; k < 8; ++k) { loff[tid * 8 + k] = run; run += lhist[tid * 8 + k]; }
        }
        __syncthreads();
        #pragma unroll
        for (int j = 0; j < EPT; ++j)
            lrec[loff[bk[j]] + pos[j]] = rec[j];          // LDS scatter
        __syncthreads();
        for (int i = tid; i < EPB; i += 256)              // dense 16KB copy-out
            bbuf[base + i] = lrec[i];
        for (int q = tid; q < NBUCK; q += 256) {
            boff[q * NBLK + blk] = base + loff[q];
            bcnt[q * NBLK + blk] = lhist[q];
        }
        return;
    }

    // ---------------- GEMM path ----------------
    __bf16* As = (__bf16*)smem;                // BM*SA
    __bf16* Bs = As + BM * SA;                 // BN*SB
    const int m0 = (blockIdx.x - NBLK) * BM;
    constexpr int WM = BM / 2, WN = BN / 2;
    constexpr int MT = WM / 16, NT = WN / 16;
    const int w = tid >> 6, lane = tid & 63;
    const int wm = w & 1, wn = w >> 1;
    const int lr = lane & 15;
    const int lq = lane >> 4;

    v4f acc[MT][NT] = {};

    for (int k0 = 0; k0 < K; k0 += BK) {
        {   // stage A (f32 -> bf16)
            constexpr int CH = BM * (BK / 8);
            for (int sgi = tid; sgi < CH; sgi += 256) {
                int row = sgi / (BK / 8), c8 = sgi % (BK / 8);
                int gr = m0 + row; if (gr >= M) gr = M - 1;
                const float* g = X + (size_t)gr * K + k0 + c8 * 8;
                float4 v0 = *(const float4*)g;
                float4 v1 = *(const float4*)(g + 4);
                __bf16 b[8];
                b[0] = (__bf16)v0.x; b[1] = (__bf16)v0.y; b[2] = (__bf16)v0.z; b[3] = (__bf16)v0.w;
                b[4] = (__bf16)v1.x; b[5] = (__bf16)v1.y; b[6] = (__bf16)v1.z; b[7] = (__bf16)v1.w;
                *(uint4*)&As[row * SA + c8 * 8] = *(uint4*)b;
            }
        }
        {   // stage B rows (Bt already [n][k])
            constexpr int CH = BN * (BK / 8);
            for (int sgi = tid; sgi < CH; sgi += 256) {
                int n = sgi / (BK / 8), c8 = sgi % (BK / 8);
                uint4 val = *(const uint4*)(Bt + (size_t)n * K + k0 + c8 * 8);
                *(uint4*)&Bs[n * SB + c8 * 8] = val;
            }
        }
        __syncthreads();
        #pragma unroll
        for (int kk = 0; kk < BK; kk += 32) {
            v8bf a[MT], bfr[NT];
            #pragma unroll
            for (int i = 0; i < MT; ++i)
                a[i] = *(const v8bf*)&As[(wm * WM + i * 16 + lr) * SA + kk + lq * 8];
            #pragma unroll
            for (int j = 0; j < NT; ++j)
                bfr[j] = *(const v8bf*)&Bs[(wn * WN + j * 16 + lr) * SB + kk + lq * 8];
            #pragma unroll
            for (int i = 0; i < MT; ++i)
                #pragma unroll
                for (int j = 0; j < NT; ++j)
                    acc[i][j] = __builtin_amdgcn_mfma_f32_16x16x32_bf16(a[i], bfr[j], acc[i][j], 0, 0, 0);
        }
        __syncthreads();
    }
    #pragma unroll
    for (int i = 0; i < MT; ++i)
        #pragma unroll
        for (int j = 0; j < NT; ++j)
            #pragma unroll
            for (int r = 0; r < 4; ++r) {
                int row = m0 + wm * WM + i * 16 + lq * 4 + r;
                if (row < M) {
                    int col = wn * WN + j * 16 + lr;
                    Out[(size_t)row * BN + col] = (__bf16)acc[i][j][r];
                }
            }
}

// ---------------- pass 1b: per-bucket padded-row construction --------------
// One block per bucket; exclusive ownership of a 64KB csr_pad window.
// Reads NBLK dense slices (one per build block), LDS counters assign slots.
__global__ __launch_bounds__(256) void build_rows(const uint* __restrict__ bbuf,
                                                  const int* __restrict__ boff,
                                                  const int* __restrict__ bcnt,
                                                  int* __restrict__ cnt,
                                                  float* __restrict__ inv,
                                                  int* __restrict__ csr_pad) {
    __shared__ int lcnt[256];
    const int q = blockIdx.x, tid = threadIdx.x;
    lcnt[tid] = 0;
    __syncthreads();
    const int v0 = q * 256;
    const int wid = tid >> 6, lane = tid & 63;
    for (int blk = wid; blk < NBLK; blk += 4) {
        int n   = bcnt[q * NBLK + blk];
        int off = boff[q * NBLK + blk];
        for (int i = lane; i < n; i += 64) {
            uint rec = bbuf[off + i];
            int vl = (int)(rec & 255u);
            int s  = (int)(rec >> 8);
            int p = atomicAdd(&lcnt[vl], 1);              // LDS atomic
            if (p < CAP) csr_pad[(size_t)(v0 + vl) * CAP + p] = s;
        }
    }
    __syncthreads();
    int v = v0 + tid;
    if (v < NN) {
        cnt[v] = lcnt[tid];
        inv[v] = rsqrtf((float)(lcnt[tid] + 1));
    }
}

// ------------------------------ GEMM2 (bf16 in) ----------------------------
template<int BM, int BN, int BK, int K>
__global__ __launch_bounds__(256) void gemm_bt(const __bf16* __restrict__ A,
                                               const __bf16* __restrict__ Bt,
                                               __bf16* __restrict__ Out, int M) {
    constexpr int SA = BK + 8;
    constexpr int SB = BK + 8;
    __shared__ __align__(16) __bf16 As[BM * SA];
    __shared__ __align__(16) __bf16 Bs[BN * SB];
    const int tid = threadIdx.x;
    const int m0 = blockIdx.x * BM;
    constexpr int WM = BM / 2, WN = BN / 2;
    constexpr int MT = WM / 16, NT = WN / 16;
    const int w = tid >> 6, lane = tid & 63;
    const int wm = w & 1, wn = w >> 1;
    const int lr = lane & 15;
    const int lq = lane >> 4;

    v4f acc[MT][NT] = {};

    for (int k0 = 0; k0 < K; k0 += BK) {
        {
            constexpr int CH = BM * (BK / 8);
            for (int s = tid; s < CH; s += 256) {
                int row = s / (BK / 8), c8 = s % (BK / 8);
                int gr = m0 + row; if (gr >= M) gr = M - 1;
                uint4 val = *(const uint4*)(A + (size_t)gr * K + k0 + c8 * 8);
                *(uint4*)&As[row * SA + c8 * 8] = val;
            }
        }
        {
            constexpr int CH = BN * (BK / 8);
            for (int s = tid; s < CH; s += 256) {
                int n = s / (BK / 8), c8 = s % (BK / 8);
                uint4 val = *(const uint4*)(Bt + (size_t)n * K + k0 + c8 * 8);
                *(uint4*)&Bs[n * SB + c8 * 8] = val;
            }
        }
        __syncthreads();
        #pragma unroll
        for (int kk = 0; kk < BK; kk += 32) {
            v8bf a[MT], bfr[NT];
            #pragma unroll
            for (int i = 0; i < MT; ++i)
                a[i] = *(const v8bf*)&As[(wm * WM + i * 16 + lr) * SA + kk + lq * 8];
            #pragma unroll
            for (int j = 0; j < NT; ++j)
                bfr[j] = *(const v8bf*)&Bs[(wn * WN + j * 16 + lr) * SB + kk + lq * 8];
            #pragma unroll
            for (int i = 0; i < MT; ++i)
                #pragma unroll
                for (int j = 0; j < NT; ++j)
                    acc[i][j] = __builtin_amdgcn_mfma_f32_16x16x32_bf16(a[i], bfr[j], acc[i][j], 0, 0, 0);
        }
        __syncthreads();
    }
    #pragma unroll
    for (int i = 0; i < MT; ++i)
        #pragma unroll
        for (int j = 0; j < NT; ++j)
            #pragma unroll
            for (int r = 0; r < 4; ++r) {
                int row = m0 + wm * WM + i * 16 + lq * 4 + r;
                if (row < M) {
                    int col = wn * WN + j * 16 + lr;
                    Out[(size_t)row * BN + col] = (__bf16)acc[i][j][r];
                }
            }
}

// --------------------------- aggregation kernels ---------------------------
// Wave-per-node: lane l reads csr row element l (CAP==64), coefs computed
// per-lane, broadcast via __shfl. No LDS, no barriers.

// HID=128: lane handles features {2l, 2l+1} as packed bf16x2 (uint).
__global__ __launch_bounds__(256) void agg_relu_w(const uint* __restrict__ Hin,
                                                  const float* __restrict__ inv,
                                                  const int* __restrict__ cnt,
                                                  const int* __restrict__ csr_pad,
                                                  const float* __restrict__ bias,
                                                  uint* __restrict__ Hout) {
    const int wid = threadIdx.x >> 6, lane = threadIdx.x & 63;
    const int v = blockIdx.x * 4 + wid;
    if (v >= NN) return;
    const float isv = inv[v];
    const int n_e = min(cnt[v], CAP);
    int sidx = csr_pad[(size_t)v * CAP + lane];
    if (lane >= n_e) sidx = 0;            // poison guard
    float c = inv[sidx] * isv;
    uint u = Hin[(size_t)v * 64 + lane];
    float ax = bf_lo(u) * isv * isv;
    float ay = bf_hi(u) * isv * isv;
    int j = 0;
    for (; j + 3 < n_e; j += 4) {
        int s0 = __shfl(sidx, j), s1 = __shfl(sidx, j + 1);
        int s2 = __shfl(sidx, j + 2), s3 = __shfl(sidx, j + 3);
        float c0 = __shfl(c, j), c1 = __shfl(c, j + 1);
        float c2 = __shfl(c, j + 2), c3 = __shfl(c, j + 3);
        uint h0 = Hin[(size_t)s0 * 64 + lane];
        uint h1 = Hin[(size_t)s1 * 64 + lane];
        uint h2 = Hin[(size_t)s2 * 64 + lane];
        uint h3 = Hin[(size_t)s3 * 64 + lane];
        ax += c0 * bf_lo(h0); ay += c0 * bf_hi(h0);
        ax += c1 * bf_lo(h1); ay += c1 * bf_hi(h1);
        ax += c2 * bf_lo(h2); ay += c2 * bf_hi(h2);
        ax += c3 * bf_lo(h3); ay += c3 * bf_hi(h3);
    }
    for (; j < n_e; ++j) {
        int s0 = __shfl(sidx, j);
        float c0 = __shfl(c, j);
        uint h0 = Hin[(size_t)s0 * 64 + lane];
        ax += c0 * bf_lo(h0); ay += c0 * bf_hi(h0);
    }
    float ox = fmaxf(ax + bias[2 * lane], 0.f);
    float oy = fmaxf(ay + bias[2 * lane + 1], 0.f);
    __bf16 blo = (__bf16)ox, bhi = (__bf16)oy;
    uint res = (uint)*(ushort*)&blo | ((uint)*(ushort*)&bhi << 16);
    Hout[(size_t)v * 64 + lane] = res;
}

// CLS=64: lane == class. Gather rows of 64 bf16 (128B), softmax via shfl.
__global__ __launch_bounds__(256) void agg_softmax_w(const ushort* __restrict__ Hin,
                                                     const float* __restrict__ inv,
                                                     const int* __restrict__ cnt,
                                                     const int* __restrict__ csr_pad,
                                                     const float* __restrict__ bias,
                                                     float* __restrict__ out) {
    const int wid = threadIdx.x >> 6, lane = threadIdx.x & 63;
    const int v = blockIdx.x * 4 + wid;
    if (v >= NN) return;
    const float isv = inv[v];
    const int n_e = min(cnt[v], CAP);
    int sidx = csr_pad[(size_t)v * CAP + lane];
    if (lane >= n_e) sidx = 0;
    float c = inv[sidx] * isv;
    uint u = (uint)Hin[(size_t)v * 64 + lane];
    float acc = __uint_as_float(u << 16) * isv * isv;
    int j = 0;
    for (; j + 3 < n_e; j += 4) {
        int s0 = __shfl(sidx, j), s1 = __shfl(sidx, j + 1);
        int s2 = __shfl(sidx, j + 2), s3 = __shfl(sidx, j + 3);
        float c0 = __shfl(c, j), c1 = __shfl(c, j + 1);
        float c2 = __shfl(c, j + 2), c3 = __shfl(c, j + 3);
        uint h0 = (uint)Hin[(size_t)s0 * 64 + lane];
        uint h1 = (uint)Hin[(size_t)s1 * 64 + lane];
        uint h2 = (uint)Hin[(size_t)s2 * 64 + lane];
        uint h3 = (uint)Hin[(size_t)s3 * 64 + lane];
        acc += c0 * __uint_as_float(h0 << 16);
        acc += c1 * __uint_as_float(h1 << 16);
        acc += c2 * __uint_as_float(h2 << 16);
        acc += c3 * __uint_as_float(h3 << 16);
    }
    for (; j < n_e; ++j) {
        int s0 = __shfl(sidx, j);
        float c0 = __shfl(c, j);
        uint h0 = (uint)Hin[(size_t)s0 * 64 + lane];
        acc += c0 * __uint_as_float(h0 << 16);
    }
    float o = acc + bias[lane];
    float m = o;
    #pragma unroll
    for (int off = 32; off >= 1; off >>= 1) m = fmaxf(m, __shfl_xor(m, off, 64));
    float e = __expf(o - m);
    float s = e;
    #pragma unroll
    for (int off = 32; off >= 1; off >>= 1) s += __shfl_xor(s, off, 64);
    out[(size_t)v * CLS + lane] = (o - m) - __logf(s);
}

// ------------------------------- launcher ----------------------------------

extern "C" void kernel_launch(void* const* d_in, const int* in_sizes, int n_in,
                              void* d_out, int out_size, void* d_ws, size_t ws_size,
                              hipStream_t stream) {
    const float* x   = (const float*)d_in[0];
    const int*   src = (const int*)d_in[1];
    const int*   dst = (const int*)d_in[2];
    const float* W1  = (const float*)d_in[3];
    const float* b1  = (const float*)d_in[4];
    const float* W2  = (const float*)d_in[5];
    const float* b2  = (const float*)d_in[6];
    float* out = (float*)d_out;

    char* p = (char*)d_ws;
    size_t off = 0;
    auto alloc = [&](size_t bytes) {
        off = (off + 255) & ~(size_t)255;
        char* r = p + off;
        off += bytes;
        return r;
    };
    int*    cnt     = (int*)alloc(NN * 4);
    float*  inv     = (float*)alloc(NN * 4);
    int*    boff    = (int*)alloc((size_t)NBUCK * NBLK * 4);        // 0.6 MB
    int*    bcnt    = (int*)alloc((size_t)NBUCK * NBLK * 4);        // 0.6 MB
    uint*   bbuf    = (uint*)alloc((size_t)NBLK * EPB * 4);         // 6.4 MB
    int*    csr_pad = (int*)alloc((size_t)NN * CAP * 4);            // 25.6 MB
    __bf16* W1t     = (__bf16*)alloc((size_t)F_IN * HID * 2);
    __bf16* W2t     = (__bf16*)alloc((size_t)HID * CLS * 2);
    __bf16* P1b     = (__bf16*)alloc((size_t)NN * HID * 2);
    __bf16* H1b     = (__bf16*)alloc((size_t)NN * HID * 2);
    __bf16* P2b     = (__bf16*)alloc((size_t)NN * CLS * 2);

    cvt_weights<<<(F_IN * HID + 255) / 256, 256, 0, stream>>>(W1, W2, W1t, W2t);

    // pass1a binning (391 blocks) + GEMM1 X@W1 (782 blocks), fused
    const int MB1 = (NN + 127) / 128;    // 782
    fused_bin_gemm1<128, HID, 32, F_IN><<<NBLK + MB1, 256, 0, stream>>>(
        x, W1t, P1b, NN, src, dst, boff, bcnt, bbuf);

    build_rows<<<NBUCK, 256, 0, stream>>>(bbuf, boff, bcnt, cnt, inv, csr_pad);

    agg_relu_w<<<(NN + 3) / 4, 256, 0, stream>>>((const uint*)P1b, inv, cnt, csr_pad, b1, (uint*)H1b);

    gemm_bt<128, CLS, 128, HID><<<MB1, 256, 0, stream>>>(H1b, W2t, P2b, NN);

    agg_softmax_w<<<(NN + 3) / 4, 256, 0, stream>>>((const ushort*)P2b, inv, cnt, csr_pad, b2, out);
}